// Round 3
// baseline (803.198 us; speedup 1.0000x reference)
//
#include <hip/hip_runtime.h>
#include <hip/hip_bf16.h>

#define B_   2
#define H_   16
#define SQ_  2048
#define SK_  2048
#define D_   128
#define QT   128
#define KT   64
#define NITER (SK_/KT)

using bf16x8 = __attribute__((ext_vector_type(8))) __bf16;
using bf16x4 = __attribute__((ext_vector_type(4))) __bf16;
using f32x4  = __attribute__((ext_vector_type(4))) float;
using i32x4  = __attribute__((ext_vector_type(4))) int;

#define MFMA16(a,b,c) __builtin_amdgcn_mfma_f32_16x16x32_bf16(a,b,c,0,0,0)

// ws layout (bytes): all tiles DENSE; LDS padding applied at ds_write time.
#define QOFF 0u              // bf16 Q, original layout, 16.8 MB
#define KOFF (1u<<25)        // bf16 K, original layout, 16.8 MB
#define VOFF (1u<<26)        // bf16 V^T tiles [bh*32+kt][128][64], 16.8 MB

// LDS pitches (elements). dword strides 68/36/36 are all ===4 (mod 32), so every
// b128 access pattern below spreads over 8 aligned bank-positions -> 8 dw/bank
// (the wave64 minimum). Round-2's KPITCH=160 (stride===16) was a 4x conflict.
#define KPITCH 136
#define VPITCH 72
#define PPITCH 72
#define KB_BYTES (KT*KPITCH*2)   // 17408
#define VB_BYTES (D_*VPITCH*2)   // 18432
#define PB_BYTES (QT*PPITCH*2)   // 18432

__device__ __forceinline__ bf16x8 mask8(bf16x8 p, i32x4 a, i32x4 b) {
    bf16x8 r;
    r[0] = a[0] ? p[0] : (__bf16)0.0f;
    r[1] = a[1] ? p[1] : (__bf16)0.0f;
    r[2] = a[2] ? p[2] : (__bf16)0.0f;
    r[3] = a[3] ? p[3] : (__bf16)0.0f;
    r[4] = b[0] ? p[4] : (__bf16)0.0f;
    r[5] = b[1] ? p[5] : (__bf16)0.0f;
    r[6] = b[2] ? p[6] : (__bf16)0.0f;
    r[7] = b[3] ? p[7] : (__bf16)0.0f;
    return r;
}

// ---------- prepass 1: elementwise f32 -> bf16 cast of Q and K ----------
__global__ __launch_bounds__(256)
void cast_qk(const float* __restrict__ Q, const float* __restrict__ K,
             char* __restrict__ ws)
{
    const size_t idx = (size_t)blockIdx.x * 256 + threadIdx.x;  // 524288 threads
    const float4* q4 = (const float4*)Q;
    const float4* k4 = (const float4*)K;
    bf16x4* qd = (bf16x4*)(ws + QOFF);
    bf16x4* kd = (bf16x4*)(ws + KOFF);
    #pragma unroll
    for (int i = 0; i < 4; ++i) {
        size_t f = idx + (size_t)i * 524288;   // 4*524288 = 2097152 float4 = full tensor
        float4 a = q4[f];
        qd[f] = (bf16x4){ (__bf16)a.x, (__bf16)a.y, (__bf16)a.z, (__bf16)a.w };
        float4 b = k4[f];
        kd[f] = (bf16x4){ (__bf16)b.x, (__bf16)b.y, (__bf16)b.z, (__bf16)b.w };
    }
}

// ---------- prepass 2: V 64x128 tile -> dense V^T tile [d=128][k=64] ----------
__global__ __launch_bounds__(256)
void transpose_v(const float* __restrict__ V, char* __restrict__ ws)
{
    __shared__ __align__(16) __bf16 vlds[64 * 132];
    const int blk = blockIdx.x;          // bh*32 + kt; V tiles are contiguous slices
    const int t   = threadIdx.x;

    const float4* src = (const float4*)(V + (size_t)blk * KT * D_);  // 2048 float4
    #pragma unroll
    for (int i = 0; i < 8; ++i) {        // 8*256 = 2048 float4 = exactly one tile
        int f = t + 256 * i;
        float4 v = src[f];
        int row = f >> 5, col = f & 31;  // 32 float4 per 128-wide row
        *(bf16x4*)&vlds[row * 132 + col * 4] =
            (bf16x4){ (__bf16)v.x, (__bf16)v.y, (__bf16)v.z, (__bf16)v.w };
    }
    __syncthreads();

    __bf16* dst = (__bf16*)(ws + VOFF) + (size_t)blk * (D_ * KT);   // dense 128x64
    const int d = t >> 1, h = t & 1;
    #pragma unroll
    for (int c = 0; c < 4; ++c) {
        bf16x8 frag;
        #pragma unroll
        for (int j = 0; j < 8; ++j) frag[j] = vlds[(h * 32 + c * 8 + j) * 132 + d];
        *(bf16x8*)&dst[d * KT + h * 32 + c * 8] = frag;
    }
}

// ---------- main kernel: O = dropout(Q K^T) V, software-pipelined ----------
__global__ __launch_bounds__(256, 2)
void attn_drop_kernel(const char* __restrict__ ws,
                      const int*  __restrict__ M,
                      float* __restrict__ Out)
{
    __shared__ __align__(16) char smem[KB_BYTES + VB_BYTES + PB_BYTES];  // 54272
    __bf16* Kb = (__bf16*)smem;
    __bf16* Vb = (__bf16*)(smem + KB_BYTES);
    __bf16* Pb = (__bf16*)(smem + KB_BYTES + VB_BYTES);

    const int tid  = threadIdx.x;
    const int wave = tid >> 6;
    const int lane = tid & 63;
    const int quad = lane >> 4;
    const int ln   = lane & 15;

    const int bh = blockIdx.x >> 4;
    const int qb = blockIdx.x & 15;

    const __bf16* Qbf = (const __bf16*)(ws + QOFF);
    const __bf16* Kbf = (const __bf16*)(ws + KOFF);
    const __bf16* Vtt = (const __bf16*)(ws + VOFF);
    const int* mbase = M + ((size_t)bh * SQ_ + (size_t)qb * QT) * SK_;
    float* optr = Out + ((size_t)bh * SQ_ + (size_t)qb * QT) * D_;

    // Q fragments register-resident for the whole loop
    bf16x8 qf[2][4];
    #pragma unroll
    for (int rt = 0; rt < 2; ++rt)
        #pragma unroll
        for (int s = 0; s < 4; ++s)
            qf[rt][s] = *(const bf16x8*)&Qbf[((size_t)bh*SQ_ + qb*QT + 32*wave + 16*rt + ln)*D_ + 32*s + 8*quad];

    f32x4 Oacc[2][8];
    #pragma unroll
    for (int rt = 0; rt < 2; ++rt)
        #pragma unroll
        for (int dt = 0; dt < 8; ++dt)
            Oacc[rt][dt] = (f32x4){0.f, 0.f, 0.f, 0.f};

    // staging registers (prefetched one iteration ahead)
    bf16x8 kreg[4], vreg[4];
    {
        const __bf16* kp = Kbf + ((size_t)bh*SK_ + 0*KT) * D_;
        const __bf16* vp = Vtt + (size_t)(bh*32 + 0) * (D_*KT);
        #pragma unroll
        for (int j = 0; j < 4; ++j) {
            kreg[j] = *(const bf16x8*)&kp[j*2048 + tid*8];
            vreg[j] = *(const bf16x8*)&vp[j*2048 + tid*8];
        }
    }

    #pragma unroll 1
    for (int kt = 0; kt < NITER; ++kt) {
        __syncthreads();   // previous iter's LDS reads complete
        // regs -> padded LDS (bank-uniform: 8 dw/bank, see pitch note)
        #pragma unroll
        for (int j = 0; j < 4; ++j) {
            *(bf16x8*)&Kb[(16*j + (tid>>4))*KPITCH + (tid&15)*8] = kreg[j];
            *(bf16x8*)&Vb[(32*j + (tid>>3))*VPITCH + (tid&7)*8]  = vreg[j];
        }
        __syncthreads();   // tiles ready

        // mask loads for THIS iter (A-fragment layout, nontemporal, issued first
        // so their vmcnt wait doesn't also wait on the tile prefetch below)
        i32x4 mreg[2][2][2];
        #pragma unroll
        for (int rt = 0; rt < 2; ++rt)
            #pragma unroll
            for (int ks = 0; ks < 2; ++ks)
                #pragma unroll
                for (int i = 0; i < 2; ++i)
                    mreg[rt][ks][i] = __builtin_nontemporal_load(
                        (const i32x4*)&mbase[(size_t)(32*wave + 16*rt + ln)*SK_ + kt*KT + 32*ks + 8*quad + 4*i]);

        // prefetch NEXT iter's tiles into regs; lands during compute below
        {
            const int nkt = (kt + 1 < NITER) ? kt + 1 : NITER - 1;
            const __bf16* kp = Kbf + ((size_t)bh*SK_ + nkt*KT) * D_;
            const __bf16* vp = Vtt + (size_t)(bh*32 + nkt) * (D_*KT);
            #pragma unroll
            for (int j = 0; j < 4; ++j) {
                kreg[j] = *(const bf16x8*)&kp[j*2048 + tid*8];
                vreg[j] = *(const bf16x8*)&vp[j*2048 + tid*8];
            }
        }

        // ---- S = Q K^T
        f32x4 S[2][4];
        #pragma unroll
        for (int rt = 0; rt < 2; ++rt)
            #pragma unroll
            for (int ct = 0; ct < 4; ++ct)
                S[rt][ct] = (f32x4){0.f, 0.f, 0.f, 0.f};

        #pragma unroll
        for (int s = 0; s < 4; ++s)
            #pragma unroll
            for (int ct = 0; ct < 4; ++ct) {
                bf16x8 kf = *(const bf16x8*)&Kb[(16*ct + ln)*KPITCH + 32*s + 8*quad];
                S[0][ct] = MFMA16(qf[0][s], kf, S[0][ct]);
                S[1][ct] = MFMA16(qf[1][s], kf, S[1][ct]);
            }

        // ---- P -> LDS (C-layout; wave-private rows, no barrier needed)
        #pragma unroll
        for (int rt = 0; rt < 2; ++rt)
            #pragma unroll
            for (int ct = 0; ct < 4; ++ct) {
                int row0 = 32*wave + 16*rt + 4*quad;
                #pragma unroll
                for (int r = 0; r < 4; ++r)
                    Pb[(row0 + r)*PPITCH + 16*ct + ln] = (__bf16)S[rt][ct][r];
            }

        // ---- O += dropout(P) V  (mask applied on A-fragments)
        #pragma unroll
        for (int ks = 0; ks < 2; ++ks) {
            bf16x8 pf0 = mask8(*(const bf16x8*)&Pb[(32*wave +      ln)*PPITCH + 32*ks + 8*quad],
                               mreg[0][ks][0], mreg[0][ks][1]);
            bf16x8 pf1 = mask8(*(const bf16x8*)&Pb[(32*wave + 16 + ln)*PPITCH + 32*ks + 8*quad],
                               mreg[1][ks][0], mreg[1][ks][1]);
            #pragma unroll
            for (int dt = 0; dt < 8; ++dt) {
                bf16x8 vf = *(const bf16x8*)&Vb[(16*dt + ln)*VPITCH + 32*ks + 8*quad];
                Oacc[0][dt] = MFMA16(pf0, vf, Oacc[0][dt]);
                Oacc[1][dt] = MFMA16(pf1, vf, Oacc[1][dt]);
            }
        }
    }

    // ---- epilogue: folded scale 2*sqrt(D) = 16*sqrt(2)
    const float SCALE = 22.62741699796952f;
    #pragma unroll
    for (int rt = 0; rt < 2; ++rt)
        #pragma unroll
        for (int dt = 0; dt < 8; ++dt) {
            int row0 = 32*wave + 16*rt + 4*quad;
            #pragma unroll
            for (int r = 0; r < 4; ++r)
                optr[(size_t)(row0 + r)*D_ + 16*dt + ln] = Oacc[rt][dt][r] * SCALE;
        }
}

extern "C" void kernel_launch(void* const* d_in, const int* in_sizes, int n_in,
                              void* d_out, int out_size, void* d_ws, size_t ws_size,
                              hipStream_t stream) {
    (void)in_sizes; (void)n_in; (void)ws_size; (void)out_size;
    const float* Q = (const float*)d_in[0];
    const float* K = (const float*)d_in[1];
    const float* V = (const float*)d_in[2];
    const int*   M = (const int*)d_in[3];
    float* Out = (float*)d_out;
    char* ws = (char*)d_ws;

    cast_qk<<<dim3(2048), 256, 0, stream>>>(Q, K, ws);
    transpose_v<<<dim3(B_*H_*(SK_/KT)), 256, 0, stream>>>(V, ws);
    attn_drop_kernel<<<dim3(B_*H_*(SQ_/QT)), 256, 0, stream>>>(ws, M, Out);
}